// Round 7
// baseline (730.368 us; speedup 1.0000x reference)
//
#include <hip/hip_runtime.h>

typedef unsigned int u32;
typedef unsigned short u16;
typedef __attribute__((ext_vector_type(8))) short short8;   // 8 bf16 (4 VGPRs)
typedef __attribute__((ext_vector_type(4))) float f32x4;

#define DEV __device__ __forceinline__
#define LOG2E 1.44269504089f

DEV u16 f2bf(float f) {
    u32 u = __float_as_uint(f);
    return (u16)((u + 0x7FFFu + ((u >> 16) & 1u)) >> 16);
}
DEV float bf2f(u16 h) { return __uint_as_float(((u32)h) << 16); }
DEV float frcp(float x) { return __builtin_amdgcn_rcpf(x); }
DEV float fexp2(float x) {
#if __has_builtin(__builtin_amdgcn_exp2f)
    return __builtin_amdgcn_exp2f(x);
#else
    return exp2f(x);
#endif
}
DEV u32 pack_bf16(float a, float b) {
#if __has_builtin(__builtin_amdgcn_cvt_pk_bf16_f32)
    auto v = __builtin_amdgcn_cvt_pk_bf16_f32(a, b);   // lo=a, hi=b
    u32 r; __builtin_memcpy(&r, &v, 4); return r;
#else
    return (u32)f2bf(a) | ((u32)f2bf(b) << 16);
#endif
}

// ---------------------------------------------------------------------------
// K2 (R7): FUSED gather + input-projection + LSTM recurrence, fixed.
// 8 blocks = 2 dirs x 4 batch-groups(16).
// Fix 1: LDS tiles in FRAGMENT-LINEAR order: 16B chunk (kt*4+rg)*16+cn, i.e.
//   [ch>>3][batch][ch&7] -> every ds_read_b128 is the lane-contiguous
//   canonical pattern (conflict-free); all writes land <=2-way.
// Fix 2: split MFMA accumulators (accH=bias+Whh-chain, accE=0+Wih-chain,
//   z=accH+accE): two independent 4-deep chains instead of one 8-deep.
// h history: 8-slot frag-linear ring, flushed to global every 8 steps.
// ---------------------------------------------------------------------------
__global__ __launch_bounds__(512) void k_lstm(
    const int* __restrict__ sent, const float* __restrict__ emb,
    const float* __restrict__ h0, const float* __restrict__ c0,
    const float* __restrict__ whhf, const float* __restrict__ whhb,
    const float* __restrict__ wihf, const float* __restrict__ wihb,
    const float* __restrict__ bihf, const float* __restrict__ bhhf,
    const float* __restrict__ bihb, const float* __restrict__ bhhb,
    u16* __restrict__ hfo, u16* __restrict__ hbo)
{
    const int d  = blockIdx.x >> 2, g4 = blockIdx.x & 3;
    const float* whh = d ? whhb : whhf;
    const float* wih = d ? wihb : wihf;
    const float* bih = d ? bihb : bihf;
    const float* bhh = d ? bhhb : bhhf;
    u16* ho = d ? hbo : hfo;
    const int tid = threadIdx.x;
    const int w = tid >> 6, lane = tid & 63;
    const int rg = lane >> 4, cn = lane & 15;
    const int b4 = tid & 15, part = tid >> 4;         // e-gather mapping
    const int chb = 16 * w + rg * 4;
    const int b = g4 * 16 + cn;

    __shared__ int stoks[512 * 17];                   // tokens, pad-17
    __shared__ __align__(16) u16 efrag[4][2048];      // e ring, frag-linear
    __shared__ __align__(16) u16 hfrag[8][2048];      // h ring, frag-linear

    // write indices (u16 units) into frag-linear tiles
    const int ewidx = ((part >> 1) * 16 + b4) * 8 + (part & 1) * 4;
    const int hwidx = (((2 * w + (rg >> 1)) * 16) + cn) * 8 + (rg & 1) * 4;

    // A-fragments: Whh and Wih, pre-scaled by log2e.  A[m=lane&15][k=rg*8+j]
    short8 ah[4][4], ae[4][4];
    #pragma unroll
    for (int mi = 0; mi < 4; ++mi) {
        int gate = 16 * (w + 8 * mi) + cn;
        #pragma unroll
        for (int kt = 0; kt < 4; ++kt) {
            const float* ph = whh + (size_t)gate * 128 + kt * 32 + rg * 8;
            const float* pe = wih + (size_t)gate * 128 + kt * 32 + rg * 8;
            float4 h0v = *(const float4*)ph, h1v = *(const float4*)(ph + 4);
            float4 e0v = *(const float4*)pe, e1v = *(const float4*)(pe + 4);
            union { short8 v; u32 u[4]; } sh, se;
            sh.u[0] = pack_bf16(h0v.x * LOG2E, h0v.y * LOG2E);
            sh.u[1] = pack_bf16(h0v.z * LOG2E, h0v.w * LOG2E);
            sh.u[2] = pack_bf16(h1v.x * LOG2E, h1v.y * LOG2E);
            sh.u[3] = pack_bf16(h1v.z * LOG2E, h1v.w * LOG2E);
            se.u[0] = pack_bf16(e0v.x * LOG2E, e0v.y * LOG2E);
            se.u[1] = pack_bf16(e0v.z * LOG2E, e0v.w * LOG2E);
            se.u[2] = pack_bf16(e1v.x * LOG2E, e1v.y * LOG2E);
            se.u[3] = pack_bf16(e1v.z * LOG2E, e1v.w * LOG2E);
            ah[mi][kt] = sh.v;
            ae[mi][kt] = se.v;
        }
    }
    f32x4 bs4[4];
    #pragma unroll
    for (int mi = 0; mi < 4; ++mi)
        #pragma unroll
        for (int r = 0; r < 4; ++r) {
            int g = 16 * (w + 8 * mi) + 4 * rg + r;
            bs4[mi][r] = (bih[g] + bhh[g]) * LOG2E;
        }
    float cst[4];
    {
        float4 cv = *(const float4*)(c0 + ((size_t)d * 64 + b) * 128 + chb);
        cst[0]=cv.x; cst[1]=cv.y; cst[2]=cv.z; cst[3]=cv.w;
    }
    {   // token preload: thread tid owns sentence position s=tid (16 ints)
        const int4* sp = (const int4*)(sent + tid * 64 + g4 * 16);
        int4 t0 = sp[0], t1 = sp[1], t2 = sp[2], t3 = sp[3];
        int* dst = &stoks[tid * 17];
        dst[0]=t0.x; dst[1]=t0.y; dst[2]=t0.z; dst[3]=t0.w;
        dst[4]=t1.x; dst[5]=t1.y; dst[6]=t1.z; dst[7]=t1.w;
        dst[8]=t2.x; dst[9]=t2.y; dst[10]=t2.z; dst[11]=t2.w;
        dst[12]=t3.x; dst[13]=t3.y; dst[14]=t3.z; dst[15]=t3.w;
    }
    {   // h0 -> ring slot 7 (= step -1)
        float4 hv = *(const float4*)(h0 + ((size_t)d * 64 + b) * 128 + chb);
        uint2 st0;
        st0.x = pack_bf16(hv.x, hv.y);
        st0.y = pack_bf16(hv.z, hv.w);
        *(uint2*)&hfrag[7][hwidx] = st0;
    }
    // prime efrag[0..1] = e(step 0,1); pA/pB = raw e(step 2,3)
    #pragma unroll
    for (int k = 0; k < 2; ++k) {
        int s = d ? (511 - k) : k;
        int tok = sent[s * 64 + g4 * 16 + b4];
        float4 ev = *(const float4*)(emb + (size_t)tok * 128 + part * 4);
        uint2 wv; wv.x = pack_bf16(ev.x, ev.y); wv.y = pack_bf16(ev.z, ev.w);
        *(uint2*)&efrag[k][ewidx] = wv;
    }
    float4 pA, pB;
    { int s = d ? 509 : 2; int tok = sent[s*64 + g4*16 + b4];
      pA = *(const float4*)(emb + (size_t)tok * 128 + part * 4); }
    { int s = d ? 508 : 3; int tok = sent[s*64 + g4*16 + b4];
      pB = *(const float4*)(emb + (size_t)tok * 128 + part * 4); }
    __syncthreads();

#define SUB(U, PEND)                                                         \
    {                                                                        \
        const int t = it * 8 + U;                                            \
        short8 hb[4], eb[4];                                                 \
        const u16* hrd = &hfrag[(U + 7) & 7][0];                             \
        const u16* erd = &efrag[U & 3][0];                                   \
        _Pragma("unroll") for (int kt = 0; kt < 4; ++kt) {                   \
            hb[kt] = *(const short8*)&hrd[(kt * 64 + lane) * 8];             \
            eb[kt] = *(const short8*)&erd[(kt * 64 + lane) * 8];             \
        }                                                                    \
        f32x4 z[4];                                                          \
        _Pragma("unroll") for (int mi = 0; mi < 4; ++mi) {                   \
            f32x4 aH = bs4[mi];                                              \
            f32x4 aE = {0.f, 0.f, 0.f, 0.f};                                 \
            _Pragma("unroll") for (int kt = 0; kt < 4; ++kt) {               \
                aH = __builtin_amdgcn_mfma_f32_16x16x32_bf16(                \
                    ah[mi][kt], hb[kt], aH, 0, 0, 0);                        \
                aE = __builtin_amdgcn_mfma_f32_16x16x32_bf16(                \
                    ae[mi][kt], eb[kt], aE, 0, 0, 0);                        \
            }                                                                \
            z[mi] = aH + aE;                                                 \
        }                                                                    \
        {                                                                    \
            uint2 wv; wv.x = pack_bf16(PEND.x, PEND.y);                      \
            wv.y = pack_bf16(PEND.z, PEND.w);                                \
            *(uint2*)&efrag[(U + 2) & 3][ewidx] = wv;                        \
            int s_ = d ? (511 - (t + 4)) : (t + 4);                          \
            s_ = s_ < 0 ? 0 : (s_ > 511 ? 511 : s_);                         \
            int tok = stoks[s_ * 17 + b4];                                   \
            PEND = *(const float4*)(emb + (size_t)tok * 128 + part * 4);     \
        }                                                                    \
        float hnew[4];                                                       \
        _Pragma("unroll") for (int r = 0; r < 4; ++r) {                      \
            float zi = z[0][r], zf = z[1][r], zg = z[2][r], zo = z[3][r];    \
            float ei = fexp2(-zi);                                           \
            float ef = fexp2(-zf);                                           \
            float eo = fexp2(-zo);                                           \
            float eg = fexp2(fminf(zg + zg, 126.f));                         \
            float A = 1.f + ei, F = 1.f + ef, G = 1.f + eg, O = 1.f + eo;    \
            float AG = A * G;                                                \
            float num = fmaf(cst[r], AG, (eg - 1.f) * F);                    \
            float cc  = num * frcp(F * AG);                                  \
            cst[r] = cc;                                                     \
            float ec = fexp2(fminf(2.885390082f * cc, 126.f));               \
            hnew[r] = (ec - 1.f) * frcp(fmaf(O, ec, O));                     \
        }                                                                    \
        uint2 st2;                                                           \
        st2.x = pack_bf16(hnew[0], hnew[1]);                                 \
        st2.y = pack_bf16(hnew[2], hnew[3]);                                 \
        *(uint2*)&hfrag[U & 7][hwidx] = st2;                                 \
        asm volatile("s_waitcnt lgkmcnt(0)\n\ts_barrier" ::: "memory");      \
    }

    for (int it = 0; it < 64; ++it) {
        SUB(0, pA); SUB(1, pB); SUB(2, pA); SUB(3, pB);
        SUB(4, pA); SUB(5, pB); SUB(6, pA); SUB(7, pB);
        // flush slots 0..7 (steps it*8..it*8+7): wave ws -> slot ws.
        {
            int ws = tid >> 6, l = tid & 63;
            int s_ = it * 8 + ws;
            if (d) s_ = 511 - s_;
            const u16* slotp = &hfrag[ws][0];
            #pragma unroll
            for (int p = 0; p < 4; ++p) {
                int bb = (l >> 3) + 8 * (p >> 1);
                int jj = (l & 7) + 8 * (p & 1);
                uint4 v = *(const uint4*)&slotp[(jj * 16 + bb) * 8];
                *(uint4*)(ho + ((size_t)s_ * 64 + g4 * 16 + bb) * 128 + jj * 8) = v;
            }
            asm volatile("s_waitcnt lgkmcnt(0)\n\ts_barrier" ::: "memory");
        }
    }
#undef SUB
}

// ---------------------------------------------------------------------------
// K3: feats[s,b,t] = [hf|hb] . w_out[t] + b_out[t].   block handles 32 pos.
// ---------------------------------------------------------------------------
__global__ __launch_bounds__(256) void k_feats(
    const u16* __restrict__ hf, const u16* __restrict__ hb,
    const float* __restrict__ wout, const float* __restrict__ bout,
    float* __restrict__ feats)
{
    __shared__ u16 sf[32][136], sb[32][136];
    __shared__ float wo[7][260];
    __shared__ float bo[8];
    int tid = threadIdx.x;
    int pos0 = blockIdx.x * 32;
    {
        int r = tid >> 3, cc = (tid & 7) * 16;
        const uint4* pf = (const uint4*)(hf + (size_t)(pos0 + r) * 128 + cc);
        const uint4* pb = (const uint4*)(hb + (size_t)(pos0 + r) * 128 + cc);
        *(uint4*)&sf[r][cc]     = pf[0];
        *(uint4*)&sf[r][cc + 8] = pf[1];
        *(uint4*)&sb[r][cc]     = pb[0];
        *(uint4*)&sb[r][cc + 8] = pb[1];
    }
    for (int i = tid; i < 1792; i += 256) wo[i >> 8][i & 255] = wout[i];
    if (tid < 7) bo[tid] = bout[tid];
    __syncthreads();
    int pp = tid >> 3, tt = tid & 7;
    if (tt < 7) {
        float acc = bo[tt];
        #pragma unroll 4
        for (int ch = 0; ch < 128; ++ch)
            acc += bf2f(sf[pp][ch]) * wo[tt][ch]
                 + bf2f(sb[pp][ch]) * wo[tt][128 + ch];
        feats[(size_t)(pos0 + pp) * 7 + tt] = acc;
    }
}

// ---------------------------------------------------------------------------
// K4a: CRF chunk fold.  block=(b, chunk of 64 steps).
// ---------------------------------------------------------------------------
__global__ __launch_bounds__(64) void k_crf_chunk(
    const float* __restrict__ feats, const float* __restrict__ trans,
    float* __restrict__ chunkM)
{
    int b = blockIdx.x >> 3, c = blockIdx.x & 7;
    int lane = threadIdx.x;
    int i = lane >> 3, j = lane & 7;
    __shared__ float M[8][8];
    __shared__ float fl[64][8];
    int s0 = c * 64;
    for (int idx = lane; idx < 448; idx += 64) {
        int ss = idx / 7, jj = idx - ss * 7;
        fl[ss][jj] = feats[(size_t)((s0 + ss) * 64 + b) * 7 + jj];
    }
    float tc[7];
    #pragma unroll
    for (int k = 0; k < 7; ++k) tc[k] = (j < 7) ? trans[k * 7 + j] : 0.f;
    __syncthreads();
    M[i][j] = (i < 7 && j < 7) ? (trans[i * 7 + j] + fl[0][j]) : -1e30f;
    __syncthreads();
    for (int ss = 1; ss < 64; ++ss) {
        float4 m0 = *(const float4*)&M[i][0];
        float4 m1 = *(const float4*)&M[i][4];
        float v0 = m0.x + tc[0], v1 = m0.y + tc[1], v2 = m0.z + tc[2];
        float v3 = m0.w + tc[3], v4 = m1.x + tc[4], v5 = m1.y + tc[5];
        float v6 = m1.z + tc[6];
        float mx = fmaxf(fmaxf(fmaxf(v0, v1), fmaxf(v2, v3)),
                         fmaxf(fmaxf(v4, v5), v6));
        float sm = __expf(v0 - mx) + __expf(v1 - mx) + __expf(v2 - mx)
                 + __expf(v3 - mx) + __expf(v4 - mx) + __expf(v5 - mx)
                 + __expf(v6 - mx);
        float r = mx + __logf(sm) + fl[ss][j];
        __syncthreads();
        if (i < 7 && j < 7) M[i][j] = r;
        __syncthreads();
    }
    if (i < 7 && j < 7)
        chunkM[(size_t)(b * 8 + c) * 49 + i * 7 + j] = M[i][j];
}

// ---------------------------------------------------------------------------
// K4b: fold 8 chunk matrices + alpha0 + STOP row; gold score; atomicAdd.
// ---------------------------------------------------------------------------
__global__ __launch_bounds__(64) void k_crf_final(
    const float* __restrict__ chunkM, const float* __restrict__ trans,
    const int* __restrict__ tags, const float* __restrict__ feats,
    float* __restrict__ out)
{
    int b = blockIdx.x;
    int lane = threadIdx.x;
    __shared__ float P[8][49];
    __shared__ float Tl[49];
    __shared__ float av[2][8];
    __shared__ int   tg[512];
    for (int idx = lane; idx < 392; idx += 64)
        P[idx / 49][idx % 49] = chunkM[(size_t)b * 392 + idx];
    if (lane < 49) Tl[lane] = trans[lane];
    for (int idx = lane; idx < 512; idx += 64) tg[idx] = tags[(size_t)b * 512 + idx];
    if (lane < 8) av[0][lane] = (lane == 5) ? 0.f : -1e4f;
    __syncthreads();
    int cur = 0;
    for (int cch = 0; cch < 8; ++cch) {
        if (lane < 7) {
            float vv[7], mx = -1e30f;
            #pragma unroll
            for (int ii = 0; ii < 7; ++ii) {
                vv[ii] = av[cur][ii] + P[cch][ii * 7 + lane];
                mx = fmaxf(mx, vv[ii]);
            }
            float sm = 0.f;
            #pragma unroll
            for (int ii = 0; ii < 7; ++ii) sm += __expf(vv[ii] - mx);
            av[cur ^ 1][lane] = mx + __logf(sm);
        }
        __syncthreads();
        cur ^= 1;
    }
    float mx = -1e30f, uu[7];
    #pragma unroll
    for (int jj = 0; jj < 7; ++jj) {
        uu[jj] = av[cur][jj] + Tl[6 * 7 + jj];
        mx = fmaxf(mx, uu[jj]);
    }
    float sm = 0.f;
    #pragma unroll
    for (int jj = 0; jj < 7; ++jj) sm += __expf(uu[jj] - mx);
    float fwd = mx + __logf(sm);
    float acc = 0.f;
    for (int ss = lane; ss < 512; ss += 64) {
        int tn = tg[ss];
        int tp = (ss == 0) ? 5 : tg[ss - 1];
        acc += Tl[tn * 7 + tp] + feats[(size_t)(ss * 64 + b) * 7 + tn];
    }
    #pragma unroll
    for (int mk = 32; mk >= 1; mk >>= 1) acc += __shfl_xor(acc, mk, 64);
    if (lane == 0) {
        float gold = acc + Tl[6 * 7 + tg[511]];
        atomicAdd(out, (fwd - gold) * (1.0f / 64.0f));
    }
}

// ---------------------------------------------------------------------------
extern "C" void kernel_launch(void* const* d_in, const int* in_sizes, int n_in,
                              void* d_out, int out_size, void* d_ws, size_t ws_size,
                              hipStream_t stream) {
    const int*   sent = (const int*)d_in[0];
    const int*   tags = (const int*)d_in[1];
    const float* h0   = (const float*)d_in[2];
    const float* c0   = (const float*)d_in[3];
    const float* emb  = (const float*)d_in[4];
    const float* wihf = (const float*)d_in[5];
    const float* whhf = (const float*)d_in[6];
    const float* bihf = (const float*)d_in[7];
    const float* bhhf = (const float*)d_in[8];
    const float* wihb = (const float*)d_in[9];
    const float* whhb = (const float*)d_in[10];
    const float* bihb = (const float*)d_in[11];
    const float* bhhb = (const float*)d_in[12];
    const float* wout = (const float*)d_in[13];
    const float* bout = (const float*)d_in[14];
    const float* trn  = (const float*)d_in[15];

    char* ws = (char*)d_ws;
    u16*   hfp    = (u16*)(ws);                       //  8,388,608 B
    u16*   hbp    = (u16*)(ws + 8388608);             //  8,388,608 B
    float* feats  = (float*)(ws + 16777216);          //    917,504 B
    float* chunkM = (float*)(ws + 17694720);          //    100,352 B

    hipMemsetAsync(d_out, 0, 4, stream);
    k_lstm<<<8, 512, 0, stream>>>(sent, emb, h0, c0, whhf, whhb, wihf, wihb,
                                  bihf, bhhf, bihb, bhhb, hfp, hbp);
    k_feats<<<1024, 256, 0, stream>>>(hfp, hbp, wout, bout, feats);
    k_crf_chunk<<<512, 64, 0, stream>>>(feats, trn, chunkM);
    k_crf_final<<<64, 64, 0, stream>>>(chunkM, trn, tags, feats, (float*)d_out);
}

// Round 8
// 571.870 us; speedup vs baseline: 1.2772x; 1.2772x over previous
//
#include <hip/hip_runtime.h>

typedef unsigned int u32;
typedef unsigned short u16;
typedef __attribute__((ext_vector_type(8))) short short8;   // 8 bf16 (4 VGPRs)
typedef __attribute__((ext_vector_type(4))) float f32x4;

#define DEV __device__ __forceinline__
#define LOG2E 1.44269504089f

DEV u16 f2bf(float f) {
    u32 u = __float_as_uint(f);
    return (u16)((u + 0x7FFFu + ((u >> 16) & 1u)) >> 16);
}
DEV float bf2f(u16 h) { return __uint_as_float(((u32)h) << 16); }
DEV float frcp(float x) { return __builtin_amdgcn_rcpf(x); }
DEV float fexp2(float x) {
#if __has_builtin(__builtin_amdgcn_exp2f)
    return __builtin_amdgcn_exp2f(x);
#else
    return exp2f(x);
#endif
}
DEV u32 pack_bf16(float a, float b) {
#if __has_builtin(__builtin_amdgcn_cvt_pk_bf16_f32)
    auto v = __builtin_amdgcn_cvt_pk_bf16_f32(a, b);   // lo=a, hi=b
    u32 r; __builtin_memcpy(&r, &v, 4); return r;
#else
    return (u32)f2bf(a) | ((u32)f2bf(b) << 16);
#endif
}
// extract r-th bf16 (r constant under unroll) from packed uint2
DEV float xex(uint2 v, int r) {
    u32 u = (r & 2) ? v.y : v.x;
    return (r & 1) ? __uint_as_float(u & 0xFFFF0000u) : __uint_as_float(u << 16);
}

// ---------------------------------------------------------------------------
// K1 (R5-proven): fused embedding gather + input projection, MFMA, both dirs.
// 256 blocks = 2 dirs x 128 chunks of 4 s-steps; each block covers all 64
// batch (4 N-tiles).  X layout = C-frag-swizzled; pre-scaled by log2e.
// ---------------------------------------------------------------------------
__global__ __launch_bounds__(512) void k_inproj2(
    const int* __restrict__ sent, const float* __restrict__ emb,
    const float* __restrict__ wihf, const float* __restrict__ bihf, const float* __restrict__ bhhf,
    const float* __restrict__ wihb, const float* __restrict__ bihb, const float* __restrict__ bhhb,
    u16* __restrict__ Xf, u16* __restrict__ Xb)
{
    int blk = blockIdx.x;
    int d  = blk >> 7;
    int sc = blk & 127;                    // 4 s-steps per block
    const float* wih = d ? wihb : wihf;
    const float* bih = d ? bihb : bihf;
    const float* bhh = d ? bhhb : bhhf;
    u16* X = d ? Xb : Xf;
    int tid = threadIdx.x;
    int w = tid >> 6, lane = tid & 63;
    int rg = lane >> 4, cn = lane & 15;

    short8 afr[4][4];                      // A[m=lane&15][k=(lane>>4)*8+j]
    #pragma unroll
    for (int mi = 0; mi < 4; ++mi) {
        int gate = 16 * (w + 8 * mi) + cn;
        #pragma unroll
        for (int kt = 0; kt < 4; ++kt) {
            const float* p = wih + (size_t)gate * 128 + kt * 32 + rg * 8;
            float4 f0 = *(const float4*)p;
            float4 f1 = *(const float4*)(p + 4);
            union { short8 v; u32 u[4]; } sv;
            sv.u[0] = pack_bf16(f0.x, f0.y);
            sv.u[1] = pack_bf16(f0.z, f0.w);
            sv.u[2] = pack_bf16(f1.x, f1.y);
            sv.u[3] = pack_bf16(f1.z, f1.w);
            afr[mi][kt] = sv.v;
        }
    }
    float bs[4][4];
    #pragma unroll
    for (int mi = 0; mi < 4; ++mi)
        #pragma unroll
        for (int r = 0; r < 4; ++r) {
            int g = 16 * (w + 8 * mi) + 4 * rg + r;
            bs[mi][r] = bih[g] + bhh[g];
        }

    __shared__ u16 tile[2][64][136];       // 2 s-steps x 64 batch x 128 ch
    #pragma unroll
    for (int stage = 0; stage < 2; ++stage) {
        if (stage) __syncthreads();        // protect LDS reuse
        {
            int row = tid >> 2, q = tid & 3;   // 128 rows (2s x 64b), 32 ch each
            int sl = row >> 6, bb = row & 63;
            int tok = sent[(sc * 4 + stage * 2 + sl) * 64 + bb];
            const float* er = emb + (size_t)tok * 128 + q * 32;
            u16* dst = &tile[sl][bb][q * 32];
            #pragma unroll
            for (int u = 0; u < 4; ++u) {
                float4 a = *(const float4*)(er + u * 8);
                float4 c = *(const float4*)(er + u * 8 + 4);
                uint4 st;
                st.x = pack_bf16(a.x, a.y); st.y = pack_bf16(a.z, a.w);
                st.z = pack_bf16(c.x, c.y); st.w = pack_bf16(c.z, c.w);
                *(uint4*)(dst + u * 8) = st;
            }
        }
        __syncthreads();
        #pragma unroll
        for (int ss = 0; ss < 2; ++ss) {
            int s = sc * 4 + stage * 2 + ss;
            #pragma unroll
            for (int nt = 0; nt < 4; ++nt) {       // N-tile = batch group g4
                short8 bfr[4];
                #pragma unroll
                for (int kt = 0; kt < 4; ++kt)
                    bfr[kt] = *(const short8*)&tile[ss][nt * 16 + cn][kt * 32 + rg * 8];
                #pragma unroll
                for (int mi = 0; mi < 4; ++mi) {
                    f32x4 acc = {0.f, 0.f, 0.f, 0.f};
                    #pragma unroll
                    for (int kt = 0; kt < 4; ++kt)
                        acc = __builtin_amdgcn_mfma_f32_16x16x32_bf16(afr[mi][kt], bfr[kt], acc, 0, 0, 0);
                    size_t base = (((size_t)s * 4 + nt) * 32 + (w + 8 * mi)) * 256
                                + (size_t)rg * 64 + (size_t)cn * 4;
                    uint2 st;
                    st.x = pack_bf16((acc[0] + bs[mi][0]) * LOG2E, (acc[1] + bs[mi][1]) * LOG2E);
                    st.y = pack_bf16((acc[2] + bs[mi][2]) * LOG2E, (acc[3] + bs[mi][3]) * LOG2E);
                    *(uint2*)(X + base) = st;
                }
            }
        }
    }
}

// ---------------------------------------------------------------------------
// K2 (R4-proven, 394us): bidirectional LSTM recurrence.  8 blocks.
// t unrolled by 2 (static LDS ping-pong), MFMA acc initialized from X, two
// independent use-then-reload X register sets (depth-2 prefetch), global
// h-store before the barrier, LDS-only barrier.
// ---------------------------------------------------------------------------
__global__ __launch_bounds__(512) void k_lstm(
    const float* __restrict__ h0, const float* __restrict__ c0,
    const float* __restrict__ whhf, const float* __restrict__ whhb,
    const u16* __restrict__ Xf, const u16* __restrict__ Xb,
    u16* __restrict__ hfo, u16* __restrict__ hbo)
{
    int d  = blockIdx.x >> 2, g4 = blockIdx.x & 3;
    const float* whh = d ? whhb : whhf;
    const u16*   X   = d ? Xb   : Xf;
    u16*         ho  = d ? hbo  : hfo;
    int w = threadIdx.x >> 6, lane = threadIdx.x & 63;
    int rg = lane >> 4, cn = lane & 15;

    short8 afr[4][4];                  // whh * log2e, A-frag layout
    #pragma unroll
    for (int mi = 0; mi < 4; ++mi) {
        int gate = 16 * (w + 8 * mi) + cn;
        #pragma unroll
        for (int kt = 0; kt < 4; ++kt) {
            const float* p = whh + (size_t)gate * 128 + kt * 32 + rg * 8;
            float4 f0 = *(const float4*)p;
            float4 f1 = *(const float4*)(p + 4);
            union { short8 v; u32 u[4]; } sv;
            sv.u[0] = pack_bf16(f0.x * LOG2E, f0.y * LOG2E);
            sv.u[1] = pack_bf16(f0.z * LOG2E, f0.w * LOG2E);
            sv.u[2] = pack_bf16(f1.x * LOG2E, f1.y * LOG2E);
            sv.u[3] = pack_bf16(f1.z * LOG2E, f1.w * LOG2E);
            afr[mi][kt] = sv.v;
        }
    }
    int b = g4 * 16 + cn;
    int chb = 16 * w + rg * 4;
    float cst[4];
    {
        float4 cv = *(const float4*)(c0 + ((size_t)d * 64 + b) * 128 + chb);
        cst[0]=cv.x; cst[1]=cv.y; cst[2]=cv.z; cst[3]=cv.w;
    }
    __shared__ u16 hbuf[2][16][136];
    {
        float4 hv = *(const float4*)(h0 + ((size_t)d * 64 + b) * 128 + chb);
        uint2 st0;
        st0.x = pack_bf16(hv.x, hv.y);
        st0.y = pack_bf16(hv.z, hv.w);
        *(uint2*)&hbuf[0][cn][chb] = st0;
    }
    __syncthreads();

    int s0 = d ? 511 : 0;
    const int sdelta = d ? -32768 : 32768;      // X u16 elems per s-step
    const ptrdiff_t hdelta = d ? -8192 : 8192;  // 64*128 u16 per s-step
    size_t lof = (size_t)rg * 64 + (size_t)cn * 4;

    const u16* pa[4]; const u16* pb[4];
    uint2 xA[4], xB[4];
    #pragma unroll
    for (int mi = 0; mi < 4; ++mi) {
        const u16* base = X + (((size_t)s0 * 4 + g4) * 32 + (w + 8 * mi)) * 256 + lof;
        xA[mi] = *(const uint2*)base;
        xB[mi] = *(const uint2*)(base + sdelta);
        pa[mi] = base + 2 * sdelta;
        pb[mi] = base + 3 * sdelta;
    }
    u16* hop = ho + ((size_t)s0 * 64 + b) * 128 + chb;

#define LSTM_STEP(RB, WB, XC, XP)                                            \
    do {                                                                     \
        short8 bfr[4];                                                       \
        _Pragma("unroll")                                                    \
        for (int kt = 0; kt < 4; ++kt)                                       \
            bfr[kt] = *(const short8*)&hbuf[RB][cn][kt * 32 + rg * 8];       \
        f32x4 z[4];                                                          \
        _Pragma("unroll")                                                    \
        for (int mi = 0; mi < 4; ++mi) {                                     \
            f32x4 acc;                                                       \
            acc[0] = xex(XC[mi], 0); acc[1] = xex(XC[mi], 1);                \
            acc[2] = xex(XC[mi], 2); acc[3] = xex(XC[mi], 3);                \
            _Pragma("unroll")                                                \
            for (int kt = 0; kt < 4; ++kt)                                   \
                acc = __builtin_amdgcn_mfma_f32_16x16x32_bf16(               \
                    afr[mi][kt], bfr[kt], acc, 0, 0, 0);                     \
            z[mi] = acc;                                                     \
            XC[mi] = *(const uint2*)XP[mi];                                  \
            XP[mi] += 2 * sdelta;                                            \
        }                                                                    \
        float hnew[4];                                                       \
        _Pragma("unroll")                                                    \
        for (int r = 0; r < 4; ++r) {                                        \
            float zi = z[0][r], zf = z[1][r], zg = z[2][r], zo = z[3][r];    \
            float ei = fexp2(-zi);                                           \
            float ef = fexp2(-zf);                                           \
            float eo = fexp2(-zo);                                           \
            float eg = fexp2(fminf(zg + zg, 115.f));                         \
            float A = 1.f + ei, F = 1.f + ef, G = eg + 1.f, O = 1.f + eo;    \
            float AG = A * G;                                                \
            float cc = (cst[r] * AG + (eg - 1.f) * F) * frcp(F * AG);        \
            cst[r] = cc;                                                     \
            float ec = fexp2(fminf(2.885390082f * cc, 115.f));               \
            hnew[r] = (ec - 1.f) * frcp(O * (ec + 1.f));                     \
        }                                                                    \
        uint2 st;                                                            \
        st.x = pack_bf16(hnew[0], hnew[1]);                                  \
        st.y = pack_bf16(hnew[2], hnew[3]);                                  \
        *(uint2*)&hbuf[WB][cn][chb] = st;                                    \
        *(uint2*)hop = st;                                                   \
        hop += hdelta;                                                       \
        asm volatile("s_waitcnt lgkmcnt(0)\n\ts_barrier" ::: "memory");      \
    } while (0)

    for (int it = 0; it < 256; ++it) {
        LSTM_STEP(0, 1, xA, pa);
        LSTM_STEP(1, 0, xB, pb);
    }
#undef LSTM_STEP
}

// ---------------------------------------------------------------------------
// K3: feats[s,b,t] = [hf|hb] . w_out[t] + b_out[t].   block handles 32 pos.
// ---------------------------------------------------------------------------
__global__ __launch_bounds__(256) void k_feats(
    const u16* __restrict__ hf, const u16* __restrict__ hb,
    const float* __restrict__ wout, const float* __restrict__ bout,
    float* __restrict__ feats)
{
    __shared__ u16 sf[32][136], sb[32][136];
    __shared__ float wo[7][260];
    __shared__ float bo[8];
    int tid = threadIdx.x;
    int pos0 = blockIdx.x * 32;
    {
        int r = tid >> 3, cc = (tid & 7) * 16;
        const uint4* pf = (const uint4*)(hf + (size_t)(pos0 + r) * 128 + cc);
        const uint4* pb = (const uint4*)(hb + (size_t)(pos0 + r) * 128 + cc);
        *(uint4*)&sf[r][cc]     = pf[0];
        *(uint4*)&sf[r][cc + 8] = pf[1];
        *(uint4*)&sb[r][cc]     = pb[0];
        *(uint4*)&sb[r][cc + 8] = pb[1];
    }
    for (int i = tid; i < 1792; i += 256) wo[i >> 8][i & 255] = wout[i];
    if (tid < 7) bo[tid] = bout[tid];
    __syncthreads();
    int pp = tid >> 3, tt = tid & 7;
    if (tt < 7) {
        float acc = bo[tt];
        #pragma unroll 4
        for (int ch = 0; ch < 128; ++ch)
            acc += bf2f(sf[pp][ch]) * wo[tt][ch]
                 + bf2f(sb[pp][ch]) * wo[tt][128 + ch];
        feats[(size_t)(pos0 + pp) * 7 + tt] = acc;
    }
}

// ---------------------------------------------------------------------------
// K4a: CRF chunk fold.  block=(b, chunk of 64 steps).  512 blocks.
// ---------------------------------------------------------------------------
__global__ __launch_bounds__(64) void k_crf_chunk(
    const float* __restrict__ feats, const float* __restrict__ trans,
    float* __restrict__ chunkM)
{
    int b = blockIdx.x >> 3, c = blockIdx.x & 7;
    int lane = threadIdx.x;
    int i = lane >> 3, j = lane & 7;
    __shared__ float M[8][8];
    __shared__ float fl[64][8];
    int s0 = c * 64;
    for (int idx = lane; idx < 448; idx += 64) {
        int ss = idx / 7, jj = idx - ss * 7;
        fl[ss][jj] = feats[(size_t)((s0 + ss) * 64 + b) * 7 + jj];
    }
    float tc[7];
    #pragma unroll
    for (int k = 0; k < 7; ++k) tc[k] = (j < 7) ? trans[k * 7 + j] : 0.f;
    __syncthreads();
    M[i][j] = (i < 7 && j < 7) ? (trans[i * 7 + j] + fl[0][j]) : -1e30f;
    __syncthreads();
    for (int ss = 1; ss < 64; ++ss) {
        float4 m0 = *(const float4*)&M[i][0];
        float4 m1 = *(const float4*)&M[i][4];
        float v0 = m0.x + tc[0], v1 = m0.y + tc[1], v2 = m0.z + tc[2];
        float v3 = m0.w + tc[3], v4 = m1.x + tc[4], v5 = m1.y + tc[5];
        float v6 = m1.z + tc[6];
        float mx = fmaxf(fmaxf(fmaxf(v0, v1), fmaxf(v2, v3)),
                         fmaxf(fmaxf(v4, v5), v6));
        float sm = __expf(v0 - mx) + __expf(v1 - mx) + __expf(v2 - mx)
                 + __expf(v3 - mx) + __expf(v4 - mx) + __expf(v5 - mx)
                 + __expf(v6 - mx);
        float r = mx + __logf(sm) + fl[ss][j];
        __syncthreads();
        if (i < 7 && j < 7) M[i][j] = r;
        __syncthreads();
    }
    if (i < 7 && j < 7)
        chunkM[(size_t)(b * 8 + c) * 49 + i * 7 + j] = M[i][j];
}

// ---------------------------------------------------------------------------
// K4b (R8): SINGLE-block final fold.  8 waves x 8 batches; lane = k*8+j
// handles (batch w*8+k, tag j).  Folds 8 chunk matrices via shuffle-lse,
// adds STOP row, computes gold with all 512 threads, block-reduces, and
// writes d_out[0] with a plain store (no memset node, no atomic).
// ---------------------------------------------------------------------------
__global__ __launch_bounds__(512) void k_crf_final(
    const float* __restrict__ chunkM, const float* __restrict__ trans,
    const int* __restrict__ tags, const float* __restrict__ feats,
    float* __restrict__ out)
{
    int tid = threadIdx.x;
    int w = tid >> 6, lane = tid & 63;
    int k = lane >> 3, j = lane & 7;
    int b = w * 8 + k;
    bool jv = (j < 7);
    __shared__ float Tl[49];
    __shared__ float red[512];
    __shared__ float fsh[64];
    if (tid < 49) Tl[tid] = trans[tid];
    __syncthreads();

    float av = (j == 5) ? 0.f : -1e4f;          // alpha0
    #pragma unroll
    for (int c = 0; c < 8; ++c) {
        float a0 = __shfl(av, k * 8 + 0, 64);
        float a1 = __shfl(av, k * 8 + 1, 64);
        float a2 = __shfl(av, k * 8 + 2, 64);
        float a3 = __shfl(av, k * 8 + 3, 64);
        float a4 = __shfl(av, k * 8 + 4, 64);
        float a5 = __shfl(av, k * 8 + 5, 64);
        float a6 = __shfl(av, k * 8 + 6, 64);
        if (jv) {
            const float* Pp = chunkM + ((size_t)b * 8 + c) * 49 + j;
            float v0 = a0 + Pp[0],  v1 = a1 + Pp[7],  v2 = a2 + Pp[14];
            float v3 = a3 + Pp[21], v4 = a4 + Pp[28], v5 = a5 + Pp[35];
            float v6 = a6 + Pp[42];
            float mx = fmaxf(fmaxf(fmaxf(v0, v1), fmaxf(v2, v3)),
                             fmaxf(fmaxf(v4, v5), v6));
            float sm = __expf(v0 - mx) + __expf(v1 - mx) + __expf(v2 - mx)
                     + __expf(v3 - mx) + __expf(v4 - mx) + __expf(v5 - mx)
                     + __expf(v6 - mx);
            av = mx + __logf(sm);
        }
    }
    // fwd = lse_j(av[j] + trans[STOP=6][j]) over the 8-lane j-group
    float u = jv ? (av + Tl[42 + j]) : -1e30f;
    float m = u;
    #pragma unroll
    for (int off = 1; off < 8; off <<= 1) m = fmaxf(m, __shfl_xor(m, off, 64));
    float e = jv ? __expf(u - m) : 0.f;
    #pragma unroll
    for (int off = 1; off < 8; off <<= 1) e += __shfl_xor(e, off, 64);
    float fwd = m + __logf(e);
    if (j == 0) fsh[b] = fwd;

    // gold: thread handles batch tb, quarter q (64 steps each)
    int tb = tid & 63, q = tid >> 6;
    const int* tgp = tags + (size_t)tb * 512;
    float acc = 0.f;
    int tp = (q == 0) ? 5 : tgp[q * 64 - 1];
    for (int ss = q * 64; ss < q * 64 + 64; ++ss) {
        int tn = tgp[ss];
        acc += Tl[tn * 7 + tp] + feats[(size_t)(ss * 64 + tb) * 7 + tn];
        tp = tn;
    }
    if (q == 7) acc += Tl[42 + tgp[511]];
    red[tid] = acc;
    __syncthreads();
    if (tid < 64) {
        float g = red[tid];
        #pragma unroll
        for (int qq = 1; qq < 8; ++qq) g += red[tid + 64 * qq];
        red[tid] = fsh[tid] - g;
    }
    __syncthreads();
    if (tid < 64) {
        float v = red[tid];
        #pragma unroll
        for (int off = 1; off < 64; off <<= 1) v += __shfl_xor(v, off, 64);
        if (tid == 0) out[0] = v * (1.0f / 64.0f);
    }
}

// ---------------------------------------------------------------------------
extern "C" void kernel_launch(void* const* d_in, const int* in_sizes, int n_in,
                              void* d_out, int out_size, void* d_ws, size_t ws_size,
                              hipStream_t stream) {
    const int*   sent = (const int*)d_in[0];
    const int*   tags = (const int*)d_in[1];
    const float* h0   = (const float*)d_in[2];
    const float* c0   = (const float*)d_in[3];
    const float* emb  = (const float*)d_in[4];
    const float* wihf = (const float*)d_in[5];
    const float* whhf = (const float*)d_in[6];
    const float* bihf = (const float*)d_in[7];
    const float* bhhf = (const float*)d_in[8];
    const float* wihb = (const float*)d_in[9];
    const float* whhb = (const float*)d_in[10];
    const float* bihb = (const float*)d_in[11];
    const float* bhhb = (const float*)d_in[12];
    const float* wout = (const float*)d_in[13];
    const float* bout = (const float*)d_in[14];
    const float* trn  = (const float*)d_in[15];

    char* ws = (char*)d_ws;
    u16*   Xf     = (u16*)(ws);                       // 33,554,432 B
    u16*   Xb     = (u16*)(ws + 33554432);            // 33,554,432 B
    u16*   hfp    = (u16*)(ws + 67108864);            //  8,388,608 B
    u16*   hbp    = (u16*)(ws + 75497472);            //  8,388,608 B
    float* feats  = (float*)(ws + 83886080);          //    917,504 B
    float* chunkM = (float*)(ws + 84803584);          //    100,352 B

    k_inproj2<<<256, 512, 0, stream>>>(sent, emb, wihf, bihf, bhhf,
                                       wihb, bihb, bhhb, Xf, Xb);
    k_lstm<<<8, 512, 0, stream>>>(h0, c0, whhf, whhb, Xf, Xb, hfp, hbp);
    k_feats<<<1024, 256, 0, stream>>>(hfp, hbp, wout, bout, feats);
    k_crf_chunk<<<512, 64, 0, stream>>>(feats, trn, chunkM);
    k_crf_final<<<1, 512, 0, stream>>>(chunkM, trn, tags, feats, (float*)d_out);
}